// Round 9
// baseline (250.958 us; speedup 1.0000x reference)
//
#include <hip/hip_runtime.h>
#include <math.h>

#define IN_DIM 128
#define OUT_DIM 64
#define NEG_SLOPE 0.2f

typedef __attribute__((ext_vector_type(8))) short short8;
typedef __attribute__((ext_vector_type(4))) float v4f;

__device__ inline unsigned short f2bf(float f) {
    unsigned u = __float_as_uint(f);
    return (unsigned short)((u + 0x7fffu + ((u >> 16) & 1u)) >> 16);   // RNE
}

// ---------------------------------------------------------------- MFMA GEMM (+ fused degree/rank)
// h(fp32) = X@W via bf16 MFMA (fp32 accum); el = h@a_l, er = h@a_r from acc tiles.
// Wave owns 64 rows (4 M-tiles of 16). A-frags straight from global, B-frags in VGPRs.
// Prologue: this block's slice of edges does degree counting + rank assignment
// (atomics overlap with the MFMA work; saves a standalone dispatch).
__global__ __launch_bounds__(256) void gemm_mfma_kernel(
        const float* __restrict__ X, const float* __restrict__ W,
        const float* __restrict__ a_l, const float* __restrict__ a_r,
        float* __restrict__ h, float* __restrict__ el, float* __restrict__ er, int n,
        const int* __restrict__ dst, int* __restrict__ deg, int* __restrict__ erank, int e)
{
    const int tid  = threadIdx.x;
    const int lane = tid & 63;
    const int wv   = tid >> 6;
    const int r16  = lane & 15;     // A row / B col / D col
    const int g    = lane >> 4;     // k-group (8 k each)

    // fused degree+rank over this block's edge slice
    {
        const int per = (e + gridDim.x - 1) / gridDim.x;
        const int lo  = blockIdx.x * per;
        const int hi  = min(lo + per, e);
        for (int i = lo + tid; i < hi; i += 256)
            erank[i] = atomicAdd(&deg[dst[i]], 1);
    }

    // B-frags: bf[ks][nt][j] = W[ks*32 + g*8 + j][nt*16 + r16]
    short8 bf[4][4];
    #pragma unroll
    for (int ks = 0; ks < 4; ++ks) {
        #pragma unroll
        for (int nt = 0; nt < 4; ++nt) {
            const float* wp = W + (size_t)(ks * 32 + g * 8) * OUT_DIM + nt * 16 + r16;
            short8 b;
            #pragma unroll
            for (int j = 0; j < 8; ++j)
                b[j] = (short)f2bf(wp[(size_t)j * OUT_DIM]);
            bf[ks][nt] = b;
        }
    }

    const float alv0 = a_l[r16],      alv1 = a_l[16 + r16],
                alv2 = a_l[32 + r16], alv3 = a_l[48 + r16];
    const float arv0 = a_r[r16],      arv1 = a_r[16 + r16],
                arv2 = a_r[32 + r16], arv3 = a_r[48 + r16];

    const int wave_row0 = blockIdx.x * 256 + wv * 64;

    #pragma unroll
    for (int mt = 0; mt < 4; ++mt) {
        const int row0m = wave_row0 + mt * 16;
        if (row0m >= n) break;

        const int rowA = min(row0m + r16, n - 1);     // clamp for tail
        const float* xp = X + (size_t)rowA * IN_DIM + g * 8;

        v4f acc0 = {0.f,0.f,0.f,0.f}, acc1 = {0.f,0.f,0.f,0.f},
            acc2 = {0.f,0.f,0.f,0.f}, acc3 = {0.f,0.f,0.f,0.f};

        #pragma unroll
        for (int ks = 0; ks < 4; ++ks) {
            const float4 xa = *(const float4*)(xp + ks * 32);
            const float4 xb = *(const float4*)(xp + ks * 32 + 4);
            short8 a;
            a[0] = (short)f2bf(xa.x); a[1] = (short)f2bf(xa.y);
            a[2] = (short)f2bf(xa.z); a[3] = (short)f2bf(xa.w);
            a[4] = (short)f2bf(xb.x); a[5] = (short)f2bf(xb.y);
            a[6] = (short)f2bf(xb.z); a[7] = (short)f2bf(xb.w);
            acc0 = __builtin_amdgcn_mfma_f32_16x16x32_bf16(a, bf[ks][0], acc0, 0, 0, 0);
            acc1 = __builtin_amdgcn_mfma_f32_16x16x32_bf16(a, bf[ks][1], acc1, 0, 0, 0);
            acc2 = __builtin_amdgcn_mfma_f32_16x16x32_bf16(a, bf[ks][2], acc2, 0, 0, 0);
            acc3 = __builtin_amdgcn_mfma_f32_16x16x32_bf16(a, bf[ks][3], acc3, 0, 0, 0);
        }

        // D layout: row = g*4 + reg, col = nt*16 + r16
        #pragma unroll
        for (int reg = 0; reg < 4; ++reg) {
            const int row = row0m + g * 4 + reg;
            if (row < n) {
                float* hp = h + (size_t)row * OUT_DIM + r16;
                hp[0]  = acc0[reg];
                hp[16] = acc1[reg];
                hp[32] = acc2[reg];
                hp[48] = acc3[reg];
            }
        }

        #pragma unroll
        for (int reg = 0; reg < 4; ++reg) {
            float t = acc0[reg]*alv0 + acc1[reg]*alv1 + acc2[reg]*alv2 + acc3[reg]*alv3;
            float u = acc0[reg]*arv0 + acc1[reg]*arv1 + acc2[reg]*arv2 + acc3[reg]*arv3;
            #pragma unroll
            for (int off = 1; off < 16; off <<= 1) {
                t += __shfl_xor(t, off);
                u += __shfl_xor(u, off);
            }
            const int row = row0m + g * 4 + reg;
            if (r16 == 0 && row < n) { el[row] = t; er[row] = u; }
        }
    }
}

// ---------------------------------------------------------------- CSR build
// one-shot segment allocation: wave-prefix scan + one atomic per wave.
__global__ __launch_bounds__(256) void alloc_kernel(
        const int* __restrict__ deg, int* __restrict__ cursor,
        int2* __restrict__ seg, int n)
{
    const int i    = blockIdx.x * blockDim.x + threadIdx.x;
    const int lane = threadIdx.x & 63;
    const int d    = (i < n) ? deg[i] : 0;

    int incl = d;
    #pragma unroll
    for (int off = 1; off < 64; off <<= 1) {
        int u = __shfl_up(incl, off);
        if (lane >= off) incl += u;
    }
    int base = 0;
    if (lane == 63) base = atomicAdd(cursor, incl);
    base = __shfl(base, 63);
    if (i < n) seg[i] = make_int2(base + incl - d, d);
}

// atomic-free scatter + per-edge exp-weight computation.
// esw[p] = { src, exp(leaky_relu(el[src]+er[dst])) }  (no max subtraction:
// logits are bounded (|el|,|er| small), softmax is shift-invariant)
__global__ void scatter_w_kernel(
        const int* __restrict__ src, const int* __restrict__ dst,
        const float* __restrict__ el, const float* __restrict__ er,
        const int2* __restrict__ seg, const int* __restrict__ erank,
        int2* __restrict__ esw, int e)
{
    int i = blockIdx.x * blockDim.x + threadIdx.x;
    if (i >= e) return;
    const int s = src[i], d = dst[i];
    float x = el[s] + er[d];
    x = (x > 0.f) ? x : NEG_SLOPE * x;
    const float w = __expf(x);
    const int p = ((const int*)seg)[2 * d] + erank[i];
    esw[p] = make_int2(s, __float_as_int(w));
}

// ---------------------------------------------------------------- fused softmax + aggregate
// One wave per destination node. Half-wave per edge: lane&31 = channel pair,
// float2 gather (8B/lane). 4 edges in flight via 2-step unroll.
__global__ __launch_bounds__(256) void gat_node_kernel(
        const int2* __restrict__ esw, const int2* __restrict__ seg,
        const float* __restrict__ h, float* __restrict__ out, int n)
{
    const int node = blockIdx.x * 4 + (threadIdx.x >> 6);
    const int lane = threadIdx.x & 63;
    const int half = lane >> 5;
    const int cl   = lane & 31;
    if (node >= n) return;

    const int2 sg   = seg[node];
    const int start = sg.x;
    const int deg   = sg.y;

    float vx = 0.f, vy = 0.f;
    if (deg > 0) {
        float ax = 0.f, ay = 0.f, bx = 0.f, by = 0.f;
        if (deg <= 64) {
            int s = 0; float w = 0.f;
            if (lane < deg) {
                const int2 p = esw[start + lane];
                s = p.x; w = __int_as_float(p.y);
            }
            float dsum = w;
            #pragma unroll
            for (int off = 32; off > 0; off >>= 1) dsum += __shfl_xor(dsum, off);
            const float alpha = w * (1.f / dsum);   // lane j holds alpha_j

            int j0 = 0;
            for (; j0 + 4 <= deg; j0 += 4) {
                const int   ja = j0 + half,         jb = j0 + 2 + half;
                const float aa = __shfl(alpha, ja), ab = __shfl(alpha, jb);
                const int   sa = __shfl(s, ja),     sb = __shfl(s, jb);
                const float2 ha = *(const float2*)(h + (size_t)sa * OUT_DIM + 2 * cl);
                const float2 hb = *(const float2*)(h + (size_t)sb * OUT_DIM + 2 * cl);
                ax = fmaf(aa, ha.x, ax); ay = fmaf(aa, ha.y, ay);
                bx = fmaf(ab, hb.x, bx); by = fmaf(ab, hb.y, by);
            }
            for (; j0 < deg; j0 += 2) {
                const int j = j0 + half;
                if (j < deg) {
                    const float aj = __shfl(alpha, j);
                    const int   sj = __shfl(s, j);
                    const float2 hj = *(const float2*)(h + (size_t)sj * OUT_DIM + 2 * cl);
                    ax = fmaf(aj, hj.x, ax); ay = fmaf(aj, hj.y, ay);
                }
            }
        } else {
            // chunked (deg > 64, rare)
            float dsum = 0.f;
            for (int base = 0; base < deg; base += 64) {
                const int idx = base + lane;
                if (idx < deg) dsum += __int_as_float(esw[start + idx].y);
            }
            #pragma unroll
            for (int off = 32; off > 0; off >>= 1) dsum += __shfl_xor(dsum, off);
            const float inv = 1.f / dsum;

            for (int base = 0; base < deg; base += 64) {
                const int idx = base + lane;
                const int cnt = min(64, deg - base);
                int s = 0; float w = 0.f;
                if (idx < deg) {
                    const int2 p = esw[start + idx];
                    s = p.x; w = __int_as_float(p.y);
                }
                const float alpha = w * inv;
                int j0 = 0;
                for (; j0 + 4 <= cnt; j0 += 4) {
                    const int   ja = j0 + half,         jb = j0 + 2 + half;
                    const float aa = __shfl(alpha, ja), ab = __shfl(alpha, jb);
                    const int   sa = __shfl(s, ja),     sb = __shfl(s, jb);
                    const float2 ha = *(const float2*)(h + (size_t)sa * OUT_DIM + 2 * cl);
                    const float2 hb = *(const float2*)(h + (size_t)sb * OUT_DIM + 2 * cl);
                    ax = fmaf(aa, ha.x, ax); ay = fmaf(aa, ha.y, ay);
                    bx = fmaf(ab, hb.x, bx); by = fmaf(ab, hb.y, by);
                }
                for (; j0 < cnt; j0 += 2) {
                    const int j = j0 + half;
                    if (j < cnt) {
                        const float aj = __shfl(alpha, j);
                        const int   sj = __shfl(s, j);
                        const float2 hj = *(const float2*)(h + (size_t)sj * OUT_DIM + 2 * cl);
                        ax = fmaf(aj, hj.x, ax); ay = fmaf(aj, hj.y, ay);
                    }
                }
            }
        }
        vx = ax + bx; vy = ay + by;
        vx += __shfl_xor(vx, 32);
        vy += __shfl_xor(vy, 32);
    }
    if (half == 0) {
        float2 o; o.x = vx; o.y = vy;
        *(float2*)(out + (size_t)node * OUT_DIM + 2 * cl) = o;
    }
}

// ---------------------------------------------------------------- launch
extern "C" void kernel_launch(void* const* d_in, const int* in_sizes, int n_in,
                              void* d_out, int out_size, void* d_ws, size_t ws_size,
                              hipStream_t stream) {
    const float* X   = (const float*)d_in[0];
    const int*   ei  = (const int*)  d_in[1];
    const float* W   = (const float*)d_in[2];
    const float* a_l = (const float*)d_in[3];
    const float* a_r = (const float*)d_in[4];
    float* out = (float*)d_out;

    const int n = in_sizes[0] / IN_DIM;   // 100000
    const int e = in_sizes[1] / 2;        // 1000000
    const int* src = ei;
    const int* dst = ei + e;

    char* ws = (char*)d_ws;
    auto carve = [&](size_t bytes) {
        char* p = ws;
        ws += (bytes + 255) & ~(size_t)255;
        return p;
    };
    float* h     = (float*)carve((size_t)n * OUT_DIM * sizeof(float));   // 25.6 MB
    float* el    = (float*)carve((size_t)n * sizeof(float));
    float* er    = (float*)carve((size_t)n * sizeof(float));
    int*   degc  = (int*)  carve((size_t)(n + 1) * sizeof(int));         // deg + cursor
    int2*  seg   = (int2*) carve((size_t)n * sizeof(int2));
    int*   erank = (int*)  carve((size_t)e * sizeof(int));               // 4 MB
    int2*  esw   = (int2*) carve((size_t)e * sizeof(int2));              // 8 MB
    int*   deg    = degc;
    int*   cursor = degc + n;

    const int gemm_blocks = (n + 255) / 256;   // 391

    hipMemsetAsync(degc, 0, (size_t)(n + 1) * sizeof(int), stream);
    gemm_mfma_kernel<<<gemm_blocks, 256, 0, stream>>>(
        X, W, a_l, a_r, h, el, er, n, dst, deg, erank, e);
    alloc_kernel<<<(n + 255) / 256, 256, 0, stream>>>(deg, cursor, seg, n);
    scatter_w_kernel<<<(e + 255) / 256, 256, 0, stream>>>(src, dst, el, er, seg, erank, esw, e);
    gat_node_kernel<<<(n + 3) / 4, 256, 0, stream>>>(esw, seg, h, out, n);
}

// Round 10
// 236.407 us; speedup vs baseline: 1.0616x; 1.0616x over previous
//
#include <hip/hip_runtime.h>
#include <math.h>

#define IN_DIM 128
#define OUT_DIM 64
#define NEG_SLOPE 0.2f
#define DEG_BLOCKS 256

typedef __attribute__((ext_vector_type(8))) short short8;
typedef __attribute__((ext_vector_type(4))) float v4f;

__device__ inline unsigned short f2bf(float f) {
    unsigned u = __float_as_uint(f);
    return (unsigned short)((u + 0x7fffu + ((u >> 16) & 1u)) >> 16);   // RNE
}

// ---------------------------------------------------------------- fused GEMM + degree/rank
// Disjoint block roles: blocks [0, DEG_BLOCKS) do degree counting + rank
// assignment over edge slices; blocks [DEG_BLOCKS, ...) do the MFMA GEMM
// (1 M-tile of 16 rows per wave for TLP). The two workloads co-reside on
// the CUs and overlap instead of serializing.
__global__ __launch_bounds__(256) void gemm_degree_kernel(
        const float* __restrict__ X, const float* __restrict__ W,
        const float* __restrict__ a_l, const float* __restrict__ a_r,
        float* __restrict__ h, float* __restrict__ el, float* __restrict__ er, int n,
        const int* __restrict__ dst, int* __restrict__ deg, int* __restrict__ erank, int e)
{
    const int tid = threadIdx.x;

    if (blockIdx.x < DEG_BLOCKS) {
        // ---- degree + rank role ----
        const int per = (e + DEG_BLOCKS - 1) / DEG_BLOCKS;
        const int lo  = blockIdx.x * per;
        const int hi  = min(lo + per, e);
        for (int i = lo + tid; i < hi; i += 256)
            erank[i] = atomicAdd(&deg[dst[i]], 1);
        return;
    }

    // ---- GEMM role: wave owns one 16-row M-tile ----
    const int lane = tid & 63;
    const int wv   = tid >> 6;
    const int r16  = lane & 15;     // A row / B col / D col
    const int g    = lane >> 4;     // k-group (8 k each)

    const int row0m = (blockIdx.x - DEG_BLOCKS) * 64 + wv * 16;
    if (row0m >= n) return;

    // B-frags: bf[ks][nt][j] = W[ks*32 + g*8 + j][nt*16 + r16]
    short8 bf[4][4];
    #pragma unroll
    for (int ks = 0; ks < 4; ++ks) {
        #pragma unroll
        for (int nt = 0; nt < 4; ++nt) {
            const float* wp = W + (size_t)(ks * 32 + g * 8) * OUT_DIM + nt * 16 + r16;
            short8 b;
            #pragma unroll
            for (int j = 0; j < 8; ++j)
                b[j] = (short)f2bf(wp[(size_t)j * OUT_DIM]);
            bf[ks][nt] = b;
        }
    }

    const int rowA = min(row0m + r16, n - 1);     // clamp for tail
    const float* xp = X + (size_t)rowA * IN_DIM + g * 8;

    v4f acc0 = {0.f,0.f,0.f,0.f}, acc1 = {0.f,0.f,0.f,0.f},
        acc2 = {0.f,0.f,0.f,0.f}, acc3 = {0.f,0.f,0.f,0.f};

    #pragma unroll
    for (int ks = 0; ks < 4; ++ks) {
        const float4 xa = *(const float4*)(xp + ks * 32);
        const float4 xb = *(const float4*)(xp + ks * 32 + 4);
        short8 a;
        a[0] = (short)f2bf(xa.x); a[1] = (short)f2bf(xa.y);
        a[2] = (short)f2bf(xa.z); a[3] = (short)f2bf(xa.w);
        a[4] = (short)f2bf(xb.x); a[5] = (short)f2bf(xb.y);
        a[6] = (short)f2bf(xb.z); a[7] = (short)f2bf(xb.w);
        acc0 = __builtin_amdgcn_mfma_f32_16x16x32_bf16(a, bf[ks][0], acc0, 0, 0, 0);
        acc1 = __builtin_amdgcn_mfma_f32_16x16x32_bf16(a, bf[ks][1], acc1, 0, 0, 0);
        acc2 = __builtin_amdgcn_mfma_f32_16x16x32_bf16(a, bf[ks][2], acc2, 0, 0, 0);
        acc3 = __builtin_amdgcn_mfma_f32_16x16x32_bf16(a, bf[ks][3], acc3, 0, 0, 0);
    }

    // D layout: row = g*4 + reg, col = nt*16 + r16
    #pragma unroll
    for (int reg = 0; reg < 4; ++reg) {
        const int row = row0m + g * 4 + reg;
        if (row < n) {
            float* hp = h + (size_t)row * OUT_DIM + r16;
            hp[0]  = acc0[reg];
            hp[16] = acc1[reg];
            hp[32] = acc2[reg];
            hp[48] = acc3[reg];
        }
    }

    const float alv0 = a_l[r16],      alv1 = a_l[16 + r16],
                alv2 = a_l[32 + r16], alv3 = a_l[48 + r16];
    const float arv0 = a_r[r16],      arv1 = a_r[16 + r16],
                arv2 = a_r[32 + r16], arv3 = a_r[48 + r16];

    #pragma unroll
    for (int reg = 0; reg < 4; ++reg) {
        float t = acc0[reg]*alv0 + acc1[reg]*alv1 + acc2[reg]*alv2 + acc3[reg]*alv3;
        float u = acc0[reg]*arv0 + acc1[reg]*arv1 + acc2[reg]*arv2 + acc3[reg]*arv3;
        #pragma unroll
        for (int off = 1; off < 16; off <<= 1) {
            t += __shfl_xor(t, off);
            u += __shfl_xor(u, off);
        }
        const int row = row0m + g * 4 + reg;
        if (r16 == 0 && row < n) { el[row] = t; er[row] = u; }
    }
}

// ---------------------------------------------------------------- CSR build
// one-shot segment allocation: wave-prefix scan + one atomic per wave.
__global__ __launch_bounds__(256) void alloc_kernel(
        const int* __restrict__ deg, int* __restrict__ cursor,
        int2* __restrict__ seg, int n)
{
    const int i    = blockIdx.x * blockDim.x + threadIdx.x;
    const int lane = threadIdx.x & 63;
    const int d    = (i < n) ? deg[i] : 0;

    int incl = d;
    #pragma unroll
    for (int off = 1; off < 64; off <<= 1) {
        int u = __shfl_up(incl, off);
        if (lane >= off) incl += u;
    }
    int base = 0;
    if (lane == 63) base = atomicAdd(cursor, incl);
    base = __shfl(base, 63);
    if (i < n) seg[i] = make_int2(base + incl - d, d);
}

// atomic-free scatter + per-edge exp-weight computation.
// esw[p] = { src, exp(leaky_relu(el[src]+er[dst])) }  (no max subtraction:
// logits are bounded (|el|,|er| small), softmax is shift-invariant)
__global__ void scatter_w_kernel(
        const int* __restrict__ src, const int* __restrict__ dst,
        const float* __restrict__ el, const float* __restrict__ er,
        const int2* __restrict__ seg, const int* __restrict__ erank,
        int2* __restrict__ esw, int e)
{
    int i = blockIdx.x * blockDim.x + threadIdx.x;
    if (i >= e) return;
    const int s = src[i], d = dst[i];
    float x = el[s] + er[d];
    x = (x > 0.f) ? x : NEG_SLOPE * x;
    const float w = __expf(x);
    const int p = ((const int*)seg)[2 * d] + erank[i];
    esw[p] = make_int2(s, __float_as_int(w));
}

// ---------------------------------------------------------------- fused softmax + aggregate
// One wave per destination node. Half-wave per edge: lane&31 = channel pair,
// float2 gather (8B/lane). 4 edges in flight via 2-step unroll.
__global__ __launch_bounds__(256) void gat_node_kernel(
        const int2* __restrict__ esw, const int2* __restrict__ seg,
        const float* __restrict__ h, float* __restrict__ out, int n)
{
    const int node = blockIdx.x * 4 + (threadIdx.x >> 6);
    const int lane = threadIdx.x & 63;
    const int half = lane >> 5;
    const int cl   = lane & 31;
    if (node >= n) return;

    const int2 sg   = seg[node];
    const int start = sg.x;
    const int deg   = sg.y;

    float vx = 0.f, vy = 0.f;
    if (deg > 0) {
        float ax = 0.f, ay = 0.f, bx = 0.f, by = 0.f;
        if (deg <= 64) {
            int s = 0; float w = 0.f;
            if (lane < deg) {
                const int2 p = esw[start + lane];
                s = p.x; w = __int_as_float(p.y);
            }
            float dsum = w;
            #pragma unroll
            for (int off = 32; off > 0; off >>= 1) dsum += __shfl_xor(dsum, off);
            const float alpha = w * (1.f / dsum);   // lane j holds alpha_j

            int j0 = 0;
            for (; j0 + 4 <= deg; j0 += 4) {
                const int   ja = j0 + half,         jb = j0 + 2 + half;
                const float aa = __shfl(alpha, ja), ab = __shfl(alpha, jb);
                const int   sa = __shfl(s, ja),     sb = __shfl(s, jb);
                const float2 ha = *(const float2*)(h + (size_t)sa * OUT_DIM + 2 * cl);
                const float2 hb = *(const float2*)(h + (size_t)sb * OUT_DIM + 2 * cl);
                ax = fmaf(aa, ha.x, ax); ay = fmaf(aa, ha.y, ay);
                bx = fmaf(ab, hb.x, bx); by = fmaf(ab, hb.y, by);
            }
            for (; j0 < deg; j0 += 2) {
                const int j = j0 + half;
                if (j < deg) {
                    const float aj = __shfl(alpha, j);
                    const int   sj = __shfl(s, j);
                    const float2 hj = *(const float2*)(h + (size_t)sj * OUT_DIM + 2 * cl);
                    ax = fmaf(aj, hj.x, ax); ay = fmaf(aj, hj.y, ay);
                }
            }
        } else {
            // chunked (deg > 64, rare)
            float dsum = 0.f;
            for (int base = 0; base < deg; base += 64) {
                const int idx = base + lane;
                if (idx < deg) dsum += __int_as_float(esw[start + idx].y);
            }
            #pragma unroll
            for (int off = 32; off > 0; off >>= 1) dsum += __shfl_xor(dsum, off);
            const float inv = 1.f / dsum;

            for (int base = 0; base < deg; base += 64) {
                const int idx = base + lane;
                const int cnt = min(64, deg - base);
                int s = 0; float w = 0.f;
                if (idx < deg) {
                    const int2 p = esw[start + idx];
                    s = p.x; w = __int_as_float(p.y);
                }
                const float alpha = w * inv;
                int j0 = 0;
                for (; j0 + 4 <= cnt; j0 += 4) {
                    const int   ja = j0 + half,         jb = j0 + 2 + half;
                    const float aa = __shfl(alpha, ja), ab = __shfl(alpha, jb);
                    const int   sa = __shfl(s, ja),     sb = __shfl(s, jb);
                    const float2 ha = *(const float2*)(h + (size_t)sa * OUT_DIM + 2 * cl);
                    const float2 hb = *(const float2*)(h + (size_t)sb * OUT_DIM + 2 * cl);
                    ax = fmaf(aa, ha.x, ax); ay = fmaf(aa, ha.y, ay);
                    bx = fmaf(ab, hb.x, bx); by = fmaf(ab, hb.y, by);
                }
                for (; j0 < cnt; j0 += 2) {
                    const int j = j0 + half;
                    if (j < cnt) {
                        const float aj = __shfl(alpha, j);
                        const int   sj = __shfl(s, j);
                        const float2 hj = *(const float2*)(h + (size_t)sj * OUT_DIM + 2 * cl);
                        ax = fmaf(aj, hj.x, ax); ay = fmaf(aj, hj.y, ay);
                    }
                }
            }
        }
        vx = ax + bx; vy = ay + by;
        vx += __shfl_xor(vx, 32);
        vy += __shfl_xor(vy, 32);
    }
    if (half == 0) {
        float2 o; o.x = vx; o.y = vy;
        *(float2*)(out + (size_t)node * OUT_DIM + 2 * cl) = o;
    }
}

// ---------------------------------------------------------------- launch
extern "C" void kernel_launch(void* const* d_in, const int* in_sizes, int n_in,
                              void* d_out, int out_size, void* d_ws, size_t ws_size,
                              hipStream_t stream) {
    const float* X   = (const float*)d_in[0];
    const int*   ei  = (const int*)  d_in[1];
    const float* W   = (const float*)d_in[2];
    const float* a_l = (const float*)d_in[3];
    const float* a_r = (const float*)d_in[4];
    float* out = (float*)d_out;

    const int n = in_sizes[0] / IN_DIM;   // 100000
    const int e = in_sizes[1] / 2;        // 1000000
    const int* src = ei;
    const int* dst = ei + e;

    char* ws = (char*)d_ws;
    auto carve = [&](size_t bytes) {
        char* p = ws;
        ws += (bytes + 255) & ~(size_t)255;
        return p;
    };
    float* h     = (float*)carve((size_t)n * OUT_DIM * sizeof(float));   // 25.6 MB
    float* el    = (float*)carve((size_t)n * sizeof(float));
    float* er    = (float*)carve((size_t)n * sizeof(float));
    int*   degc  = (int*)  carve((size_t)(n + 1) * sizeof(int));         // deg + cursor
    int2*  seg   = (int2*) carve((size_t)n * sizeof(int2));
    int*   erank = (int*)  carve((size_t)e * sizeof(int));               // 4 MB
    int2*  esw   = (int2*) carve((size_t)e * sizeof(int2));              // 8 MB
    int*   deg    = degc;
    int*   cursor = degc + n;

    const int gemm_blocks = (n + 63) / 64;                 // 1563 (16 rows/wave)
    const int total_blocks = DEG_BLOCKS + gemm_blocks;     // degree role + gemm role

    hipMemsetAsync(degc, 0, (size_t)(n + 1) * sizeof(int), stream);
    gemm_degree_kernel<<<total_blocks, 256, 0, stream>>>(
        X, W, a_l, a_r, h, el, er, n, dst, deg, erank, e);
    alloc_kernel<<<(n + 255) / 256, 256, 0, stream>>>(deg, cursor, seg, n);
    scatter_w_kernel<<<(e + 255) / 256, 256, 0, stream>>>(src, dst, el, er, seg, erank, esw, e);
    gat_node_kernel<<<(n + 3) / 4, 256, 0, stream>>>(esw, seg, h, out, n);
}